// Round 5
// baseline (251.040 us; speedup 1.0000x reference)
//
#include <hip/hip_runtime.h>
#include <math.h>

#define T_DIM 2048
#define B_DIM 2
#define E_DIM 1024
#define K_DIM 64
#define H_DIM 16
#define R_DIM (T_DIM * B_DIM)   // 4096 rows, row r = t*B + b
#define CHUNK 128               // state chunk
#define NC (T_DIM / CHUNK)      // 16 chunks
#define WROWS 2176              // Wq(1024) + Wv(1024) + Wk(64) + pad(64)

typedef __bf16 bf16x8 __attribute__((ext_vector_type(8)));
typedef float f32x4 __attribute__((ext_vector_type(4)));

// ---------------------------------------------------------------------------
// fp32 -> bf16: x (4M elements), 8 per thread.
// ---------------------------------------------------------------------------
__global__ __launch_bounds__(256) void cvt_x(const float* __restrict__ X,
                                             __bf16* __restrict__ O) {
    size_t g = ((size_t)blockIdx.x * 256 + threadIdx.x) * 8;
    float4 a = *(const float4*)&X[g];
    float4 b = *(const float4*)&X[g + 4];
    bf16x8 o;
    o[0] = (__bf16)a.x; o[1] = (__bf16)a.y; o[2] = (__bf16)a.z; o[3] = (__bf16)a.w;
    o[4] = (__bf16)b.x; o[5] = (__bf16)b.y; o[6] = (__bf16)b.z; o[7] = (__bf16)b.w;
    *(bf16x8*)&O[g] = o;
}

// ---------------------------------------------------------------------------
// fp32 -> bf16 weight concat: [Wq(1024 rows); Wv(1024); Wk(64); zeros(64)].
// ---------------------------------------------------------------------------
__global__ __launch_bounds__(256) void cvt_w(const float* __restrict__ Wq,
                                             const float* __restrict__ Wv,
                                             const float* __restrict__ Wk,
                                             __bf16* __restrict__ O) {
    const size_t nq = (size_t)1024 * 1024;
    const size_t nk = (size_t)64 * 1024;
    size_t g = ((size_t)blockIdx.x * 256 + threadIdx.x) * 8;
    bf16x8 o;
    if (g < 2 * nq + nk) {
        const float* src;
        size_t off;
        if (g < nq)          { src = Wq; off = g; }
        else if (g < 2 * nq) { src = Wv; off = g - nq; }
        else                 { src = Wk; off = g - 2 * nq; }
        float4 a = *(const float4*)&src[off];
        float4 b = *(const float4*)&src[off + 4];
        o[0] = (__bf16)a.x; o[1] = (__bf16)a.y; o[2] = (__bf16)a.z; o[3] = (__bf16)a.w;
        o[4] = (__bf16)b.x; o[5] = (__bf16)b.y; o[6] = (__bf16)b.z; o[7] = (__bf16)b.w;
    } else {
#pragma unroll
        for (int i = 0; i < 8; ++i) o[i] = (__bf16)0.f;
    }
    *(bf16x8*)&O[g] = o;
}

// ---------------------------------------------------------------------------
// bf16 MFMA GEMM: C[4096 x 2176] = XB[4096x1024] @ WB[2176x1024]^T
// 128x128 tile, BK=32, 4 waves each owning 64x64 (4x4 MFMA tiles 16x16x32).
// Cols <1024 -> Cq(+bq); <2048 -> Cv(+bv); else first 64 -> Kr(+bk, stride 64).
// ---------------------------------------------------------------------------
__global__ __launch_bounds__(256) void gemm_mfma(const __bf16* __restrict__ XB,
                                                 const __bf16* __restrict__ WB,
                                                 const float* __restrict__ bq,
                                                 const float* __restrict__ bv,
                                                 const float* __restrict__ bk,
                                                 float* __restrict__ Cq,
                                                 float* __restrict__ Cv,
                                                 float* __restrict__ Kr) {
    __shared__ __bf16 Als[128 * 32];   // 8 KB
    __shared__ __bf16 Bls[128 * 32];   // 8 KB
    const int tid = threadIdx.x;
    const int lane = tid & 63;
    const int w = tid >> 6;
    const int wm = (w & 1) * 64;
    const int wn = (w >> 1) * 64;
    const int rBase = blockIdx.x * 128;
    const int cBase = blockIdx.y * 128;

    const int c0 = tid, c1 = tid + 256;
    const __bf16* gA0 = XB + (size_t)(rBase + (c0 >> 2)) * E_DIM + (c0 & 3) * 8;
    const __bf16* gA1 = XB + (size_t)(rBase + (c1 >> 2)) * E_DIM + (c1 & 3) * 8;
    const __bf16* gB0 = WB + (size_t)(cBase + (c0 >> 2)) * E_DIM + (c0 & 3) * 8;
    const __bf16* gB1 = WB + (size_t)(cBase + (c1 >> 2)) * E_DIM + (c1 & 3) * 8;
    __bf16* lA0 = Als + c0 * 8;
    __bf16* lA1 = Als + c1 * 8;
    __bf16* lB0 = Bls + c0 * 8;
    __bf16* lB1 = Bls + c1 * 8;

    const int fr = lane & 15;
    const int fk = (lane >> 4) * 8;
    const __bf16* aF = Als + (wm + fr) * 32 + fk;
    const __bf16* bF = Bls + (wn + fr) * 32 + fk;

    f32x4 acc[4][4] = {};

    for (int kk = 0; kk < E_DIM; kk += 32) {
        __syncthreads();
        __builtin_amdgcn_global_load_lds(
            (const __attribute__((address_space(1))) void*)(gA0 + kk),
            (__attribute__((address_space(3))) void*)lA0, 16, 0, 0);
        __builtin_amdgcn_global_load_lds(
            (const __attribute__((address_space(1))) void*)(gA1 + kk),
            (__attribute__((address_space(3))) void*)lA1, 16, 0, 0);
        __builtin_amdgcn_global_load_lds(
            (const __attribute__((address_space(1))) void*)(gB0 + kk),
            (__attribute__((address_space(3))) void*)lB0, 16, 0, 0);
        __builtin_amdgcn_global_load_lds(
            (const __attribute__((address_space(1))) void*)(gB1 + kk),
            (__attribute__((address_space(3))) void*)lB1, 16, 0, 0);
        __syncthreads();

        bf16x8 af[4], bfr[4];
#pragma unroll
        for (int mt = 0; mt < 4; ++mt) af[mt] = *(const bf16x8*)(aF + mt * 16 * 32);
#pragma unroll
        for (int nt = 0; nt < 4; ++nt) bfr[nt] = *(const bf16x8*)(bF + nt * 16 * 32);
#pragma unroll
        for (int mt = 0; mt < 4; ++mt)
#pragma unroll
            for (int nt = 0; nt < 4; ++nt)
                acc[mt][nt] = __builtin_amdgcn_mfma_f32_16x16x32_bf16(
                    af[mt], bfr[nt], acc[mt][nt], 0, 0, 0);
    }

    // epilogue: C/D layout col=lane&15, row=(lane>>4)*4+reg
    const int row0 = rBase + wm + (lane >> 4) * 4;
    if (cBase < 2048) {
        const float* bias;
        float* Cout;
        int colBase;
        if (cBase < 1024) { bias = bq; Cout = Cq; colBase = cBase; }
        else              { bias = bv; Cout = Cv; colBase = cBase - 1024; }
        const int col0 = colBase + wn + (lane & 15);
#pragma unroll
        for (int mt = 0; mt < 4; ++mt)
#pragma unroll
            for (int nt = 0; nt < 4; ++nt) {
                int cc = col0 + nt * 16;
                float bb = bias[cc];
#pragma unroll
                for (int r = 0; r < 4; ++r)
                    Cout[(size_t)(row0 + mt * 16 + r) * E_DIM + cc] =
                        acc[mt][nt][r] + bb;
            }
    } else {
        const int col0 = wn + (lane & 15);
#pragma unroll
        for (int mt = 0; mt < 4; ++mt)
#pragma unroll
            for (int nt = 0; nt < 4; ++nt) {
                int cc = col0 + nt * 16;
                if (cc < 64) {
                    float bb = bk[cc];
#pragma unroll
                    for (int r = 0; r < 4; ++r)
                        Kr[(size_t)(row0 + mt * 16 + r) * K_DIM + cc] =
                            acc[mt][nt][r] + bb;
                }
            }
    }
}

// ---------------------------------------------------------------------------
// qn[r, k] = mean_h softmax_k(q[r, h*64 + k]) ; one wave per row.
// ---------------------------------------------------------------------------
__global__ __launch_bounds__(64) void softmax_mean(const float* __restrict__ Q,
                                                   float* __restrict__ QN) {
    const int r = blockIdx.x;
    const int lane = threadIdx.x;
    float acc = 0.f;
#pragma unroll
    for (int h = 0; h < H_DIM; ++h) {
        float v = Q[(size_t)r * 1024 + h * 64 + lane];
        float m = v;
#pragma unroll
        for (int off = 32; off; off >>= 1) m = fmaxf(m, __shfl_xor(m, off));
        float e = expf(v - m);
        float ssum = e;
#pragma unroll
        for (int off = 32; off; off >>= 1) ssum += __shfl_xor(ssum, off);
        acc += e / ssum;
    }
    QN[(size_t)r * K_DIM + lane] = acc * (1.f / 16.f);
}

// ---------------------------------------------------------------------------
// LayerNorm over 64 (for k); one wave per row.
// ---------------------------------------------------------------------------
__global__ __launch_bounds__(64) void ln64(const float* __restrict__ Kraw,
                                           const float* __restrict__ gamma,
                                           const float* __restrict__ beta,
                                           float* __restrict__ KN) {
    const int r = blockIdx.x;
    const int lane = threadIdx.x;
    float v = Kraw[(size_t)r * K_DIM + lane];
    float s = v, s2 = v * v;
#pragma unroll
    for (int off = 32; off; off >>= 1) {
        s += __shfl_xor(s, off);
        s2 += __shfl_xor(s2, off);
    }
    float mean = s * (1.f / 64.f);
    float var = s2 * (1.f / 64.f) - mean * mean;
    float inv = rsqrtf(var + 1e-5f);
    KN[(size_t)r * K_DIM + lane] = (v - mean) * inv * gamma[lane] + beta[lane];
}

// ---------------------------------------------------------------------------
// LayerNorm over 1024 (for v), in place. Block = 256 threads.
// ---------------------------------------------------------------------------
__global__ __launch_bounds__(256) void ln1024(float* __restrict__ V,
                                              const float* __restrict__ gamma,
                                              const float* __restrict__ beta) {
    const int r = blockIdx.x;
    const int tid = threadIdx.x;
    const int lane = tid & 63, wv = tid >> 6;
    float4 v = *(const float4*)&V[(size_t)r * E_DIM + tid * 4];
    float s = v.x + v.y + v.z + v.w;
    float s2 = v.x * v.x + v.y * v.y + v.z * v.z + v.w * v.w;
#pragma unroll
    for (int off = 32; off; off >>= 1) {
        s += __shfl_xor(s, off);
        s2 += __shfl_xor(s2, off);
    }
    __shared__ float red[2][4];
    if (lane == 0) { red[0][wv] = s; red[1][wv] = s2; }
    __syncthreads();
    s = red[0][0] + red[0][1] + red[0][2] + red[0][3];
    s2 = red[1][0] + red[1][1] + red[1][2] + red[1][3];
    float mean = s * (1.f / 1024.f);
    float var = s2 * (1.f / 1024.f) - mean * mean;
    float inv = rsqrtf(var + 1e-5f);
    float4 g = *(const float4*)&gamma[tid * 4];
    float4 bb = *(const float4*)&beta[tid * 4];
    float4 o;
    o.x = (v.x - mean) * inv * g.x + bb.x;
    o.y = (v.y - mean) * inv * g.y + bb.y;
    o.z = (v.z - mean) * inv * g.z + bb.z;
    o.w = (v.w - mean) * inv * g.w + bb.w;
    *(float4*)&V[(size_t)r * E_DIM + tid * 4] = o;
}

// ---------------------------------------------------------------------------
// Pass A: per-chunk outer products O_c[b][k][e] = sum_{s in chunk} kn[s,k]*v[s,e]
// ---------------------------------------------------------------------------
__global__ __launch_bounds__(256) void chunk_outer(const float* __restrict__ KN,
                                                   const float* __restrict__ V,
                                                   float* __restrict__ O) {
    __shared__ __align__(16) float ks_l[CHUNK][64];   // 32 KB
    __shared__ __align__(16) float vs[16][256];       // 16 KB
    const int c = blockIdx.x, es = blockIdx.y, b = blockIdx.z;
    const int tid = threadIdx.x;
    const int ex = tid & 63;     // e = es*256 + ex*4
    const int kg = tid >> 6;     // k rows kg*16 .. +15

#pragma unroll
    for (int j = 0; j < 8; ++j) {
        int idx = tid + j * 256;
        int s = idx >> 4, k4 = idx & 15;
        *(float4*)&ks_l[s][k4 * 4] =
            *(const float4*)&KN[((size_t)(c * CHUNK + s) * B_DIM + b) * K_DIM + k4 * 4];
    }
    float acc[16][4];
#pragma unroll
    for (int i = 0; i < 16; ++i)
#pragma unroll
        for (int j = 0; j < 4; ++j) acc[i][j] = 0.f;

    for (int sb = 0; sb < CHUNK / 16; ++sb) {
        __syncthreads();
#pragma unroll
        for (int j = 0; j < 4; ++j) {
            int idx = tid + j * 256;
            int s = idx >> 6, e4 = idx & 63;
            *(float4*)&vs[s][e4 * 4] =
                *(const float4*)&V[((size_t)(c * CHUNK + sb * 16 + s) * B_DIM + b) * E_DIM +
                                   es * 256 + e4 * 4];
        }
        __syncthreads();
#pragma unroll
        for (int s = 0; s < 16; ++s) {
            float4 vv = *(const float4*)&vs[s][ex * 4];
#pragma unroll
            for (int i4 = 0; i4 < 4; ++i4) {
                float4 kv = *(const float4*)&ks_l[sb * 16 + s][kg * 16 + i4 * 4];
                float ka[4] = {kv.x, kv.y, kv.z, kv.w};
#pragma unroll
                for (int u = 0; u < 4; ++u) {
                    acc[i4 * 4 + u][0] += ka[u] * vv.x;
                    acc[i4 * 4 + u][1] += ka[u] * vv.y;
                    acc[i4 * 4 + u][2] += ka[u] * vv.z;
                    acc[i4 * 4 + u][3] += ka[u] * vv.w;
                }
            }
        }
    }
#pragma unroll
    for (int i = 0; i < 16; ++i) {
        int k = kg * 16 + i;
        float4 o = {acc[i][0], acc[i][1], acc[i][2], acc[i][3]};
        *(float4*)&O[(((size_t)c * B_DIM + b) * K_DIM + k) * E_DIM + es * 256 + ex * 4] = o;
    }
}

// ---------------------------------------------------------------------------
// Pass B: exclusive prefix over chunks: S_c = sum_{c'<c} O_c'
// ---------------------------------------------------------------------------
__global__ __launch_bounds__(256) void prefix_state(const float* __restrict__ O,
                                                    float* __restrict__ S) {
    const size_t p = (size_t)blockIdx.x * 256 + threadIdx.x;
    const size_t off = p * 4;
    const size_t cs = (size_t)B_DIM * K_DIM * E_DIM;
    float4 run = {0.f, 0.f, 0.f, 0.f};
    for (int c = 0; c < NC; ++c) {
        *(float4*)&S[c * cs + off] = run;
        float4 o = *(const float4*)&O[c * cs + off];
        run.x += o.x; run.y += o.y; run.z += o.z; run.w += o.w;
    }
}

// ---------------------------------------------------------------------------
// Pass C1: intra-chunk masked scores.
// SC[b][qt][q][s] = (s <= (qt%4)*32 + q) ? qn[qt*32+q]·kn[c*128+s] : 0
// Grid (64 qt, 2 b), 256 threads. Each thread: 4 q x 4 s outer-product dots.
// ---------------------------------------------------------------------------
__global__ __launch_bounds__(256) void score_intra(const float* __restrict__ QN,
                                                   const float* __restrict__ KN,
                                                   float* __restrict__ SC) {
    __shared__ __align__(16) float qs[32][68];    // 8.7 KB
    __shared__ __align__(16) float ks[CHUNK][68]; // 34.8 KB
    const int qt = blockIdx.x;
    const int b = blockIdx.y;
    const int c = qt >> 2;
    const int tid = threadIdx.x;
    const int sL = tid & 31;   // s = sL + j*32
    const int qg = tid >> 5;   // q = qg*4 + i

    // stage qn tile [32][64]
#pragma unroll
    for (int j = 0; j < 2; ++j) {
        int idx = tid + j * 256;          // float4 id, 512 total
        int q = idx >> 4, k4 = idx & 15;
        *(float4*)&qs[q][k4 * 4] =
            *(const float4*)&QN[((size_t)(qt * 32 + q) * B_DIM + b) * K_DIM + k4 * 4];
    }
    // stage kn chunk [128][64]
#pragma unroll
    for (int j = 0; j < 8; ++j) {
        int idx = tid + j * 256;          // float4 id, 2048 total
        int s = idx >> 4, k4 = idx & 15;
        *(float4*)&ks[s][k4 * 4] =
            *(const float4*)&KN[((size_t)(c * CHUNK + s) * B_DIM + b) * K_DIM + k4 * 4];
    }
    __syncthreads();

    float d[4][4] = {{0.f}};
#pragma unroll
    for (int k4 = 0; k4 < 16; ++k4) {
        float4 qv[4], kv[4];
#pragma unroll
        for (int i = 0; i < 4; ++i) qv[i] = *(const float4*)&qs[qg * 4 + i][k4 * 4];
#pragma unroll
        for (int j = 0; j < 4; ++j) kv[j] = *(const float4*)&ks[sL + j * 32][k4 * 4];
#pragma unroll
        for (int i = 0; i < 4; ++i)
#pragma unroll
            for (int j = 0; j < 4; ++j)
                d[i][j] += qv[i].x * kv[j].x + qv[i].y * kv[j].y +
                           qv[i].z * kv[j].z + qv[i].w * kv[j].w;
    }
    float* scb = SC + (((size_t)b * 64 + qt) * 32) * CHUNK;
    const int tloc = (qt & 3) * 32;
#pragma unroll
    for (int i = 0; i < 4; ++i) {
        int q = qg * 4 + i;
#pragma unroll
        for (int j = 0; j < 4; ++j) {
            int s = sL + j * 32;
            scb[(size_t)q * CHUNK + s] = (s <= tloc + q) ? d[i][j] : 0.f;
        }
    }
}

// ---------------------------------------------------------------------------
// Pass C2: fused epilogue, single out write:
//   out[t,b,e] = rsqrt(t+1) * ( qn[t]·S_c[:,e]  +  sum_s SC[t,s] * v[c*128+s,e] )
// Grid (64 qt of 32 queries, 8 es of 128 cols, 2 b), 256 threads:
//   ex = tid&31 (4 cols), tg = tid>>5 (4 query rows). LDS 40 KB -> 4 blocks/CU.
// ---------------------------------------------------------------------------
__global__ __launch_bounds__(256) void attn_out(const float* __restrict__ QN,
                                                const float* __restrict__ S,
                                                const float* __restrict__ SC,
                                                const float* __restrict__ V,
                                                float* __restrict__ OUT) {
    __shared__ __align__(16) float Sl[64][128];   // 32 KB
    __shared__ __align__(16) float qs[32][64];    // 8 KB
    const int qt = blockIdx.x;
    const int es = blockIdx.y;
    const int b = blockIdx.z;
    const int c = qt >> 2;
    const int tid = threadIdx.x;
    const int ex = tid & 31;
    const int tg = tid >> 5;
    const size_t cs = (size_t)B_DIM * K_DIM * E_DIM;

    // stage S_c slice [64 k][128 e]
#pragma unroll
    for (int j = 0; j < 8; ++j) {
        int idx = tid + j * 256;          // float4 id, 2048 total
        int k = idx >> 5, e4 = idx & 31;
        *(float4*)&Sl[k][e4 * 4] =
            *(const float4*)&S[c * cs + ((size_t)b * K_DIM + k) * E_DIM + es * 128 + e4 * 4];
    }
    // stage qn tile [32][64]
#pragma unroll
    for (int j = 0; j < 2; ++j) {
        int idx = tid + j * 256;          // float4 id, 512 total
        int q = idx >> 4, k4 = idx & 15;
        *(float4*)&qs[q][k4 * 4] =
            *(const float4*)&QN[((size_t)(qt * 32 + q) * B_DIM + b) * K_DIM + k4 * 4];
    }
    __syncthreads();

    float4 acc[4] = {};
    const float4* Sl4 = (const float4*)Sl;   // row stride 32
    const float4* qs4 = (const float4*)qs;   // row stride 16

    // inter: qn @ S_c
#pragma unroll
    for (int k4 = 0; k4 < 16; ++k4) {
        float4 sv[4], qv[4];
#pragma unroll
        for (int j = 0; j < 4; ++j) sv[j] = Sl4[(k4 * 4 + j) * 32 + ex];
#pragma unroll
        for (int i = 0; i < 4; ++i) qv[i] = qs4[(tg * 4 + i) * 16 + k4];
#pragma unroll
        for (int i = 0; i < 4; ++i) {
            acc[i].x += qv[i].x * sv[0].x + qv[i].y * sv[1].x + qv[i].z * sv[2].x + qv[i].w * sv[3].x;
            acc[i].y += qv[i].x * sv[0].y + qv[i].y * sv[1].y + qv[i].z * sv[2].y + qv[i].w * sv[3].y;
            acc[i].z += qv[i].x * sv[0].z + qv[i].y * sv[1].z + qv[i].z * sv[2].z + qv[i].w * sv[3].z;
            acc[i].w += qv[i].x * sv[0].w + qv[i].y * sv[1].w + qv[i].z * sv[2].w + qv[i].w * sv[3].w;
        }
    }

    // intra PV: scores (global, L1-broadcast) x v (global, L2)
    const int sLen4 = ((qt & 3) + 1) * 8;    // sLen/4
    const float4* SC4 = (const float4*)(SC + (((size_t)b * 64 + qt) * 32) * CHUNK);
    const float4* V4 = (const float4*)V;     // row stride 256
#pragma unroll 4
    for (int s4 = 0; s4 < sLen4; ++s4) {
        float4 vv[4];
#pragma unroll
        for (int j = 0; j < 4; ++j)
            vv[j] = V4[((size_t)(c * CHUNK + s4 * 4 + j) * B_DIM + b) * 256 + es * 32 + ex];
#pragma unroll
        for (int i = 0; i < 4; ++i) {
            float4 a = SC4[(size_t)(tg * 4 + i) * 32 + s4];
            acc[i].x += a.x * vv[0].x + a.y * vv[1].x + a.z * vv[2].x + a.w * vv[3].x;
            acc[i].y += a.x * vv[0].y + a.y * vv[1].y + a.z * vv[2].y + a.w * vv[3].y;
            acc[i].z += a.x * vv[0].z + a.y * vv[1].z + a.z * vv[2].z + a.w * vv[3].z;
            acc[i].w += a.x * vv[0].w + a.y * vv[1].w + a.z * vv[2].w + a.w * vv[3].w;
        }
    }

    // scale + single coalesced store
#pragma unroll
    for (int i = 0; i < 4; ++i) {
        int t = qt * 32 + tg * 4 + i;
        float sca = rsqrtf((float)(t + 1));
        float4 r = {acc[i].x * sca, acc[i].y * sca, acc[i].z * sca, acc[i].w * sca};
        *(float4*)&OUT[((size_t)t * B_DIM + b) * E_DIM + es * 128 + ex * 4] = r;
    }
}

// ---------------------------------------------------------------------------
extern "C" void kernel_launch(void* const* d_in, const int* in_sizes, int n_in,
                              void* d_out, int out_size, void* d_ws,
                              size_t ws_size, hipStream_t stream) {
    const float* x = (const float*)d_in[0];
    const float* Wq = (const float*)d_in[2];
    const float* bq = (const float*)d_in[3];
    const float* Wk = (const float*)d_in[4];
    const float* bk = (const float*)d_in[5];
    const float* Wv = (const float*)d_in[6];
    const float* bv = (const float*)d_in[7];
    const float* kg = (const float*)d_in[8];
    const float* kb = (const float*)d_in[9];
    const float* vg = (const float*)d_in[10];
    const float* vb = (const float*)d_in[11];
    float* out = (float*)d_out;

    float* ws = (float*)d_ws;
    float* qraw = ws;                              // 4M floats (16 MB)
    float* v = ws + (size_t)4 * 1024 * 1024;       // 4M floats (16 MB)
    float* qn = ws + (size_t)8 * 1024 * 1024;      // 256K floats
    float* kn = qn + 256 * 1024;                   // 256K floats
    float* kraw = kn + 256 * 1024;                 // 256K floats
    __bf16* xb = (__bf16*)(kraw + 256 * 1024);     // 4M bf16 (8 MB)
    __bf16* wb = xb + (size_t)4 * 1024 * 1024;     // 2176*1024 bf16 (4.46 MB)
    // qraw region reuse (dead after softmax_mean):
    float* O = qraw;                               // [0, 2M) chunk outer prods
    float* S = qraw + (size_t)2 * 1024 * 1024;     // [2M, 4M) exclusive prefix
    float* SCb = qraw;                             // [0, 512K) scores (O dead then)

    // bf16 conversions
    cvt_x<<<dim3(2048), 256, 0, stream>>>(x, xb);
    cvt_w<<<dim3(WROWS * 1024 / 8 / 256), 256, 0, stream>>>(Wq, Wv, Wk, wb);
    // fused q|v|k projection via MFMA
    gemm_mfma<<<dim3(32, 17), 256, 0, stream>>>(xb, wb, bq, bv, bk, qraw, v, kraw);
    // epilogues
    softmax_mean<<<dim3(R_DIM), 64, 0, stream>>>(qraw, qn);
    ln64<<<dim3(R_DIM), 64, 0, stream>>>(kraw, kg, kb, kn);
    ln1024<<<dim3(R_DIM), 256, 0, stream>>>(v, vg, vb);
    // chunked linear attention
    chunk_outer<<<dim3(NC, 4, B_DIM), 256, 0, stream>>>(kn, v, O);
    prefix_state<<<dim3(128), 256, 0, stream>>>(O, S);
    score_intra<<<dim3(64, B_DIM), 256, 0, stream>>>(qn, kn, SCb);
    attn_out<<<dim3(64, 8, B_DIM), 256, 0, stream>>>(qn, S, SCb, v, out);
}

// Round 6
// 205.420 us; speedup vs baseline: 1.2221x; 1.2221x over previous
//
#include <hip/hip_runtime.h>
#include <math.h>

#define T_DIM 2048
#define B_DIM 2
#define E_DIM 1024
#define K_DIM 64
#define H_DIM 16
#define R_DIM (T_DIM * B_DIM)   // 4096 rows, row r = t*B + b
#define WROWS 2176              // Wq(1024) + Wv(1024) + Wk(64) + pad(64)
#define NTILE 136               // 16*17/2 causal (qt,st) tile pairs

typedef __bf16 bf16x8 __attribute__((ext_vector_type(8)));
typedef __bf16 bf16x4 __attribute__((ext_vector_type(4)));
typedef float f32x4 __attribute__((ext_vector_type(4)));

// ---------------------------------------------------------------------------
// fp32 -> bf16: x (4M elements), 8 per thread.
// ---------------------------------------------------------------------------
__global__ __launch_bounds__(256) void cvt_x(const float* __restrict__ X,
                                             __bf16* __restrict__ O) {
    size_t g = ((size_t)blockIdx.x * 256 + threadIdx.x) * 8;
    float4 a = *(const float4*)&X[g];
    float4 b = *(const float4*)&X[g + 4];
    bf16x8 o;
    o[0] = (__bf16)a.x; o[1] = (__bf16)a.y; o[2] = (__bf16)a.z; o[3] = (__bf16)a.w;
    o[4] = (__bf16)b.x; o[5] = (__bf16)b.y; o[6] = (__bf16)b.z; o[7] = (__bf16)b.w;
    *(bf16x8*)&O[g] = o;
}

// ---------------------------------------------------------------------------
// fp32 -> bf16 weight concat: [Wq(1024 rows); Wv(1024); Wk(64); zeros(64)].
// ---------------------------------------------------------------------------
__global__ __launch_bounds__(256) void cvt_w(const float* __restrict__ Wq,
                                             const float* __restrict__ Wv,
                                             const float* __restrict__ Wk,
                                             __bf16* __restrict__ O) {
    const size_t nq = (size_t)1024 * 1024;
    const size_t nk = (size_t)64 * 1024;
    size_t g = ((size_t)blockIdx.x * 256 + threadIdx.x) * 8;
    bf16x8 o;
    if (g < 2 * nq + nk) {
        const float* src;
        size_t off;
        if (g < nq)          { src = Wq; off = g; }
        else if (g < 2 * nq) { src = Wv; off = g - nq; }
        else                 { src = Wk; off = g - 2 * nq; }
        float4 a = *(const float4*)&src[off];
        float4 b = *(const float4*)&src[off + 4];
        o[0] = (__bf16)a.x; o[1] = (__bf16)a.y; o[2] = (__bf16)a.z; o[3] = (__bf16)a.w;
        o[4] = (__bf16)b.x; o[5] = (__bf16)b.y; o[6] = (__bf16)b.z; o[7] = (__bf16)b.w;
    } else {
#pragma unroll
        for (int i = 0; i < 8; ++i) o[i] = (__bf16)0.f;
    }
    *(bf16x8*)&O[g] = o;
}

// ---------------------------------------------------------------------------
// bf16 MFMA GEMM: C[4096 x 2176] = XB[4096x1024] @ WB[2176x1024]^T
// 128x128 tile, BK=32, 4 waves each owning 64x64 (4x4 MFMA tiles 16x16x32).
// Cols <1024 -> Cq(+bq); <2048 -> Cv(+bv); else first 64 -> Kr(+bk, stride 64).
// ---------------------------------------------------------------------------
__global__ __launch_bounds__(256) void gemm_mfma(const __bf16* __restrict__ XB,
                                                 const __bf16* __restrict__ WB,
                                                 const float* __restrict__ bq,
                                                 const float* __restrict__ bv,
                                                 const float* __restrict__ bk,
                                                 float* __restrict__ Cq,
                                                 float* __restrict__ Cv,
                                                 float* __restrict__ Kr) {
    __shared__ __bf16 Als[128 * 32];   // 8 KB
    __shared__ __bf16 Bls[128 * 32];   // 8 KB
    const int tid = threadIdx.x;
    const int lane = tid & 63;
    const int w = tid >> 6;
    const int wm = (w & 1) * 64;
    const int wn = (w >> 1) * 64;
    const int rBase = blockIdx.x * 128;
    const int cBase = blockIdx.y * 128;

    const int c0 = tid, c1 = tid + 256;
    const __bf16* gA0 = XB + (size_t)(rBase + (c0 >> 2)) * E_DIM + (c0 & 3) * 8;
    const __bf16* gA1 = XB + (size_t)(rBase + (c1 >> 2)) * E_DIM + (c1 & 3) * 8;
    const __bf16* gB0 = WB + (size_t)(cBase + (c0 >> 2)) * E_DIM + (c0 & 3) * 8;
    const __bf16* gB1 = WB + (size_t)(cBase + (c1 >> 2)) * E_DIM + (c1 & 3) * 8;
    __bf16* lA0 = Als + c0 * 8;
    __bf16* lA1 = Als + c1 * 8;
    __bf16* lB0 = Bls + c0 * 8;
    __bf16* lB1 = Bls + c1 * 8;

    const int fr = lane & 15;
    const int fk = (lane >> 4) * 8;
    const __bf16* aF = Als + (wm + fr) * 32 + fk;
    const __bf16* bF = Bls + (wn + fr) * 32 + fk;

    f32x4 acc[4][4] = {};

    for (int kk = 0; kk < E_DIM; kk += 32) {
        __syncthreads();
        __builtin_amdgcn_global_load_lds(
            (const __attribute__((address_space(1))) void*)(gA0 + kk),
            (__attribute__((address_space(3))) void*)lA0, 16, 0, 0);
        __builtin_amdgcn_global_load_lds(
            (const __attribute__((address_space(1))) void*)(gA1 + kk),
            (__attribute__((address_space(3))) void*)lA1, 16, 0, 0);
        __builtin_amdgcn_global_load_lds(
            (const __attribute__((address_space(1))) void*)(gB0 + kk),
            (__attribute__((address_space(3))) void*)lB0, 16, 0, 0);
        __builtin_amdgcn_global_load_lds(
            (const __attribute__((address_space(1))) void*)(gB1 + kk),
            (__attribute__((address_space(3))) void*)lB1, 16, 0, 0);
        __syncthreads();

        bf16x8 af[4], bfr[4];
#pragma unroll
        for (int mt = 0; mt < 4; ++mt) af[mt] = *(const bf16x8*)(aF + mt * 16 * 32);
#pragma unroll
        for (int nt = 0; nt < 4; ++nt) bfr[nt] = *(const bf16x8*)(bF + nt * 16 * 32);
#pragma unroll
        for (int mt = 0; mt < 4; ++mt)
#pragma unroll
            for (int nt = 0; nt < 4; ++nt)
                acc[mt][nt] = __builtin_amdgcn_mfma_f32_16x16x32_bf16(
                    af[mt], bfr[nt], acc[mt][nt], 0, 0, 0);
    }

    const int row0 = rBase + wm + (lane >> 4) * 4;
    if (cBase < 2048) {
        const float* bias;
        float* Cout;
        int colBase;
        if (cBase < 1024) { bias = bq; Cout = Cq; colBase = cBase; }
        else              { bias = bv; Cout = Cv; colBase = cBase - 1024; }
        const int col0 = colBase + wn + (lane & 15);
#pragma unroll
        for (int mt = 0; mt < 4; ++mt)
#pragma unroll
            for (int nt = 0; nt < 4; ++nt) {
                int cc = col0 + nt * 16;
                float bb = bias[cc];
#pragma unroll
                for (int r = 0; r < 4; ++r)
                    Cout[(size_t)(row0 + mt * 16 + r) * E_DIM + cc] =
                        acc[mt][nt][r] + bb;
            }
    } else {
        const int col0 = wn + (lane & 15);
#pragma unroll
        for (int mt = 0; mt < 4; ++mt)
#pragma unroll
            for (int nt = 0; nt < 4; ++nt) {
                int cc = col0 + nt * 16;
                if (cc < 64) {
                    float bb = bk[cc];
#pragma unroll
                    for (int r = 0; r < 4; ++r)
                        Kr[(size_t)(row0 + mt * 16 + r) * K_DIM + cc] =
                            acc[mt][nt][r] + bb;
                }
            }
    }
}

// ---------------------------------------------------------------------------
// qn[r,k] = mean_h softmax_k(q[r,h*64+k]) -> bf16. 4 waves x 4 heads each.
// ---------------------------------------------------------------------------
__global__ __launch_bounds__(256) void softmax_mean(const float* __restrict__ Q,
                                                    __bf16* __restrict__ QNB) {
    const int r = blockIdx.x;
    const int tid = threadIdx.x;
    const int lane = tid & 63, wv = tid >> 6;
    float acc = 0.f;
#pragma unroll
    for (int h4 = 0; h4 < 4; ++h4) {
        int h = wv * 4 + h4;
        float v = Q[(size_t)r * 1024 + h * 64 + lane];
        float m = v;
#pragma unroll
        for (int off = 32; off; off >>= 1) m = fmaxf(m, __shfl_xor(m, off));
        float e = expf(v - m);
        float ssum = e;
#pragma unroll
        for (int off = 32; off; off >>= 1) ssum += __shfl_xor(ssum, off);
        acc += e / ssum;
    }
    __shared__ float red[4][64];
    red[wv][lane] = acc;
    __syncthreads();
    if (tid < 64) {
        float s = red[0][tid] + red[1][tid] + red[2][tid] + red[3][tid];
        QNB[(size_t)r * K_DIM + tid] = (__bf16)(s * (1.f / 16.f));
    }
}

// ---------------------------------------------------------------------------
// LayerNorm over 64 (for k) -> bf16; one wave per row.
// ---------------------------------------------------------------------------
__global__ __launch_bounds__(64) void ln64(const float* __restrict__ Kraw,
                                           const float* __restrict__ gamma,
                                           const float* __restrict__ beta,
                                           __bf16* __restrict__ KNB) {
    const int r = blockIdx.x;
    const int lane = threadIdx.x;
    float v = Kraw[(size_t)r * K_DIM + lane];
    float s = v, s2 = v * v;
#pragma unroll
    for (int off = 32; off; off >>= 1) {
        s += __shfl_xor(s, off);
        s2 += __shfl_xor(s2, off);
    }
    float mean = s * (1.f / 64.f);
    float var = s2 * (1.f / 64.f) - mean * mean;
    float inv = rsqrtf(var + 1e-5f);
    KNB[(size_t)r * K_DIM + lane] = (__bf16)((v - mean) * inv * gamma[lane] + beta[lane]);
}

// ---------------------------------------------------------------------------
// LayerNorm over 1024 (for v), in place fp32. Block = 256 threads.
// ---------------------------------------------------------------------------
__global__ __launch_bounds__(256) void ln1024(float* __restrict__ V,
                                              const float* __restrict__ gamma,
                                              const float* __restrict__ beta) {
    const int r = blockIdx.x;
    const int tid = threadIdx.x;
    const int lane = tid & 63, wv = tid >> 6;
    float4 v = *(const float4*)&V[(size_t)r * E_DIM + tid * 4];
    float s = v.x + v.y + v.z + v.w;
    float s2 = v.x * v.x + v.y * v.y + v.z * v.z + v.w * v.w;
#pragma unroll
    for (int off = 32; off; off >>= 1) {
        s += __shfl_xor(s, off);
        s2 += __shfl_xor(s2, off);
    }
    __shared__ float red[2][4];
    if (lane == 0) { red[0][wv] = s; red[1][wv] = s2; }
    __syncthreads();
    s = red[0][0] + red[0][1] + red[0][2] + red[0][3];
    s2 = red[1][0] + red[1][1] + red[1][2] + red[1][3];
    float mean = s * (1.f / 1024.f);
    float var = s2 * (1.f / 1024.f) - mean * mean;
    float inv = rsqrtf(var + 1e-5f);
    float4 g = *(const float4*)&gamma[tid * 4];
    float4 bb = *(const float4*)&beta[tid * 4];
    float4 o;
    o.x = (v.x - mean) * inv * g.x + bb.x;
    o.y = (v.y - mean) * inv * g.y + bb.y;
    o.z = (v.z - mean) * inv * g.z + bb.z;
    o.w = (v.w - mean) * inv * g.w + bb.w;
    *(float4*)&V[(size_t)r * E_DIM + tid * 4] = o;
}

// ---------------------------------------------------------------------------
// Transpose+cvt: v fp32 [t*2+b][e] -> vbT bf16 [b][e][t]. 64x64 tiles via LDS.
// ---------------------------------------------------------------------------
__global__ __launch_bounds__(256) void transpose_v(const float* __restrict__ V,
                                                   __bf16* __restrict__ VT) {
    __shared__ float tile[64][65];
    const int tb = blockIdx.x, eb = blockIdx.y, b = blockIdx.z;
    const int tid = threadIdx.x;
#pragma unroll
    for (int j = 0; j < 4; ++j) {
        int idx = tid + j * 256;           // 1024 float4
        int tl = idx >> 4, e4 = idx & 15;
        *(float4*)&tile[tl][e4 * 4] =
            *(const float4*)&V[((size_t)(tb * 64 + tl) * B_DIM + b) * E_DIM + eb * 64 + e4 * 4];
    }
    __syncthreads();
#pragma unroll
    for (int j = 0; j < 4; ++j) {
        int idx = tid + j * 256;           // 1024 groups of 4 t
        int e = idx >> 4, t4 = idx & 15;
        bf16x4 o;
#pragma unroll
        for (int i = 0; i < 4; ++i) o[i] = (__bf16)tile[t4 * 4 + i][e];
        *(bf16x4*)&VT[((size_t)b * E_DIM + eb * 64 + e) * T_DIM + tb * 64 + t4 * 4] = o;
    }
}

// ---------------------------------------------------------------------------
// scoreK: all causal 128x128 score tiles, masked, bf16.
//   P[b][tile][q][s] = (s_glob<=t_glob) ? qn[t]·kn[s] : 0,  tile=(qt,st)
// MFMA with A=knb (M=s), B=qnb (N=q) so each lane's 4 C-regs are s-contiguous
// at fixed q -> packed b64 global writes into row-major [q][s].
// Grid (136, B). 4 waves split q (32 each).
// ---------------------------------------------------------------------------
__global__ __launch_bounds__(256) void scoreK(const __bf16* __restrict__ QNB,
                                              const __bf16* __restrict__ KNB,
                                              __bf16* __restrict__ Pg) {
    const int tileId = blockIdx.x;
    const int b = blockIdx.y;
    int qt = 0, rem = tileId;
    while (rem > qt) { rem -= (qt + 1); ++qt; }
    const int st = rem;
    const int tid = threadIdx.x;
    const int lane = tid & 63;
    const int w = tid >> 6;
    const int qL = lane & 15;
    const int quad = lane >> 4;

    f32x4 acc[8][2] = {};
#pragma unroll
    for (int kit = 0; kit < 2; ++kit) {
        bf16x8 bfr[2];
#pragma unroll
        for (int nt = 0; nt < 2; ++nt) {
            int q = w * 32 + nt * 16 + qL;
            bfr[nt] = *(const bf16x8*)&QNB[((size_t)(qt * 128 + q) * B_DIM + b) * K_DIM +
                                           kit * 32 + quad * 8];
        }
#pragma unroll
        for (int mt = 0; mt < 8; ++mt) {
            int s = mt * 16 + qL;
            bf16x8 af = *(const bf16x8*)&KNB[((size_t)(st * 128 + s) * B_DIM + b) * K_DIM +
                                             kit * 32 + quad * 8];
#pragma unroll
            for (int nt = 0; nt < 2; ++nt)
                acc[mt][nt] = __builtin_amdgcn_mfma_f32_16x16x32_bf16(
                    af, bfr[nt], acc[mt][nt], 0, 0, 0);
        }
    }
    // mask diagonal tile, cvt, packed store
    __bf16* pb = Pg + ((size_t)(b * NTILE + tileId)) * 128 * 128;
#pragma unroll
    for (int mt = 0; mt < 8; ++mt)
#pragma unroll
        for (int nt = 0; nt < 2; ++nt) {
            int q = w * 32 + nt * 16 + qL;
            int s0 = mt * 16 + quad * 4;
            bf16x4 o;
#pragma unroll
            for (int r = 0; r < 4; ++r) {
                float val = acc[mt][nt][r];
                if (qt == st && (s0 + r) > q) val = 0.f;
                o[r] = (__bf16)val;
            }
            *(bf16x4*)&pb[(size_t)q * 128 + s0] = o;
        }
}

// ---------------------------------------------------------------------------
// flashPV: out[t,b,e] = rsqrt(t+1) * sum_{tiles st<=qt} sum_s P[q,s]·v[s,e]
// Grid (qt=16, es=8, b=2) = 256 blocks, 4 waves split q. LDS: one VT tile
// [128e][136s] bf16 (34.8 KB -> 4 blocks/CU). A=VT (M=e), B=P (N=q) -> D[e][q],
// transposed through per-wave LDS scratch for coalesced stores.
// ---------------------------------------------------------------------------
__global__ __launch_bounds__(256) void flashPV(const __bf16* __restrict__ Pg,
                                               const __bf16* __restrict__ VT,
                                               float* __restrict__ OUT) {
    __shared__ __align__(16) unsigned char smem[128 * 136 * 2];
    __bf16* vts = (__bf16*)smem;
    const int qt = blockIdx.x;
    const int es = blockIdx.y;
    const int b = blockIdx.z;
    const int tid = threadIdx.x;
    const int lane = tid & 63;
    const int w = tid >> 6;
    const int qL = lane & 15;
    const int quad = lane >> 4;
    const int tileBase = qt * (qt + 1) / 2;

    f32x4 acc[8][2] = {};

    for (int st = 0; st <= qt; ++st) {
        __syncthreads();
        // stage VT tile [128 e][128 s] -> LDS stride 136
#pragma unroll
        for (int j = 0; j < 8; ++j) {
            int idx = tid + j * 256;         // 2048 chunks of 8 bf16
            int e = idx >> 4, sc = idx & 15;
            *(bf16x8*)&vts[e * 136 + sc * 8] =
                *(const bf16x8*)&VT[((size_t)b * E_DIM + es * 128 + e) * T_DIM +
                                    st * 128 + sc * 8];
        }
        __syncthreads();
        const __bf16* pb = Pg + ((size_t)(b * NTILE + tileBase + st)) * 128 * 128;
#pragma unroll
        for (int kit = 0; kit < 4; ++kit) {
            bf16x8 bfr[2];
#pragma unroll
            for (int nt = 0; nt < 2; ++nt) {
                int q = w * 32 + nt * 16 + qL;
                bfr[nt] = *(const bf16x8*)&pb[(size_t)q * 128 + kit * 32 + quad * 8];
            }
#pragma unroll
            for (int mt = 0; mt < 8; ++mt) {
                bf16x8 af = *(const bf16x8*)&vts[(mt * 16 + qL) * 136 + kit * 32 + quad * 8];
#pragma unroll
                for (int nt = 0; nt < 2; ++nt)
                    acc[mt][nt] = __builtin_amdgcn_mfma_f32_16x16x32_bf16(
                        af, bfr[nt], acc[mt][nt], 0, 0, 0);
            }
        }
    }
    __syncthreads();   // VT dead; reuse smem as per-wave transpose scratch

    float* tb = (float*)smem + w * 640;     // [32 q][20 e-slots]
#pragma unroll
    for (int mt = 0; mt < 8; ++mt) {
#pragma unroll
        for (int nt = 0; nt < 2; ++nt)
            *(f32x4*)&tb[(nt * 16 + qL) * 20 + quad * 4] = acc[mt][nt];
#pragma unroll
        for (int j = 0; j < 2; ++j) {
            int fid = lane + j * 64;         // 128 float4 = 32q x 16e
            int q = fid >> 2, e4 = fid & 3;
            float4 val = *(const float4*)&tb[q * 20 + e4 * 4];
            int t = qt * 128 + w * 32 + q;
            float sca = rsqrtf((float)(t + 1));
            float4 r = {val.x * sca, val.y * sca, val.z * sca, val.w * sca};
            *(float4*)&OUT[((size_t)t * B_DIM + b) * E_DIM + es * 128 + mt * 16 + e4 * 4] = r;
        }
    }
}

// ---------------------------------------------------------------------------
extern "C" void kernel_launch(void* const* d_in, const int* in_sizes, int n_in,
                              void* d_out, int out_size, void* d_ws,
                              size_t ws_size, hipStream_t stream) {
    const float* x = (const float*)d_in[0];
    const float* Wq = (const float*)d_in[2];
    const float* bq = (const float*)d_in[3];
    const float* Wk = (const float*)d_in[4];
    const float* bk = (const float*)d_in[5];
    const float* Wv = (const float*)d_in[6];
    const float* bv = (const float*)d_in[7];
    const float* kg = (const float*)d_in[8];
    const float* kb = (const float*)d_in[9];
    const float* vg = (const float*)d_in[10];
    const float* vb = (const float*)d_in[11];
    float* out = (float*)d_out;

    float* ws = (float*)d_ws;
    float* qraw = ws;                              // 4M floats (16 MB)
    float* v = ws + (size_t)4 * 1024 * 1024;       // 4M floats (16 MB)
    float* kraw = ws + (size_t)8 * 1024 * 1024;    // 256K floats (1 MB)
    __bf16* xb = (__bf16*)(kraw + 256 * 1024);     // 4M bf16 (8 MB)
    __bf16* wb = xb + (size_t)4 * 1024 * 1024;     // WROWS*1024 bf16 (4.46 MB)
    __bf16* qnb = wb + (size_t)WROWS * 1024;       // 256K bf16 (0.5 MB)
    __bf16* knb = qnb + 256 * 1024;                // 256K bf16 (0.5 MB)
    // aliases (dead regions):
    __bf16* Pg = (__bf16*)qraw;                    // 136*2*16384 bf16 (8.9 MB), after softmax
    __bf16* vbT = xb;                              // 2*1024*2048 bf16 (8 MB), after gemm

    // bf16 conversions
    cvt_x<<<dim3(2048), 256, 0, stream>>>(x, xb);
    cvt_w<<<dim3(WROWS * 1024 / 8 / 256), 256, 0, stream>>>(Wq, Wv, Wk, wb);
    // fused q|v|k projection via MFMA
    gemm_mfma<<<dim3(32, 17), 256, 0, stream>>>(xb, wb, bq, bv, bk, qraw, v, kraw);
    // epilogues -> bf16 operands
    softmax_mean<<<dim3(R_DIM), 256, 0, stream>>>(qraw, qnb);
    ln64<<<dim3(R_DIM), 64, 0, stream>>>(kraw, kg, kb, knb);
    ln1024<<<dim3(R_DIM), 256, 0, stream>>>(v, vg, vb);
    transpose_v<<<dim3(T_DIM / 64, E_DIM / 64, B_DIM), 256, 0, stream>>>(v, vbT);
    // causal attention tail via MFMA
    scoreK<<<dim3(NTILE, B_DIM), 256, 0, stream>>>(qnb, knb, Pg);
    flashPV<<<dim3(16, 8, B_DIM), 256, 0, stream>>>(Pg, vbT, out);
}

// Round 7
// 191.910 us; speedup vs baseline: 1.3081x; 1.0704x over previous
//
#include <hip/hip_runtime.h>
#include <math.h>

#define T_DIM 2048
#define B_DIM 2
#define E_DIM 1024
#define K_DIM 64
#define H_DIM 16
#define R_DIM (T_DIM * B_DIM)   // 4096 rows, row r = t*B + b
#define WROWS 2176              // Wq(1024) + Wv(1024) + Wk(64) + pad(64)
#define NTILE 136               // 16*17/2 causal (qt,st) tile pairs

typedef __bf16 bf16x8 __attribute__((ext_vector_type(8)));
typedef __bf16 bf16x4 __attribute__((ext_vector_type(4)));
typedef float f32x4 __attribute__((ext_vector_type(4)));

// ---------------------------------------------------------------------------
// fp32 -> bf16: x (4M elements), 8 per thread.
// ---------------------------------------------------------------------------
__global__ __launch_bounds__(256) void cvt_x(const float* __restrict__ X,
                                             __bf16* __restrict__ O) {
    size_t g = ((size_t)blockIdx.x * 256 + threadIdx.x) * 8;
    float4 a = *(const float4*)&X[g];
    float4 b = *(const float4*)&X[g + 4];
    bf16x8 o;
    o[0] = (__bf16)a.x; o[1] = (__bf16)a.y; o[2] = (__bf16)a.z; o[3] = (__bf16)a.w;
    o[4] = (__bf16)b.x; o[5] = (__bf16)b.y; o[6] = (__bf16)b.z; o[7] = (__bf16)b.w;
    *(bf16x8*)&O[g] = o;
}

// ---------------------------------------------------------------------------
// fp32 -> bf16 weight concat: [Wq(1024 rows); Wv(1024); Wk(64); zeros(64)].
// ---------------------------------------------------------------------------
__global__ __launch_bounds__(256) void cvt_w(const float* __restrict__ Wq,
                                             const float* __restrict__ Wv,
                                             const float* __restrict__ Wk,
                                             __bf16* __restrict__ O) {
    const size_t nq = (size_t)1024 * 1024;
    const size_t nk = (size_t)64 * 1024;
    size_t g = ((size_t)blockIdx.x * 256 + threadIdx.x) * 8;
    bf16x8 o;
    if (g < 2 * nq + nk) {
        const float* src;
        size_t off;
        if (g < nq)          { src = Wq; off = g; }
        else if (g < 2 * nq) { src = Wv; off = g - nq; }
        else                 { src = Wk; off = g - 2 * nq; }
        float4 a = *(const float4*)&src[off];
        float4 b = *(const float4*)&src[off + 4];
        o[0] = (__bf16)a.x; o[1] = (__bf16)a.y; o[2] = (__bf16)a.z; o[3] = (__bf16)a.w;
        o[4] = (__bf16)b.x; o[5] = (__bf16)b.y; o[6] = (__bf16)b.z; o[7] = (__bf16)b.w;
    } else {
#pragma unroll
        for (int i = 0; i < 8; ++i) o[i] = (__bf16)0.f;
    }
    *(bf16x8*)&O[g] = o;
}

// ---------------------------------------------------------------------------
// bf16 MFMA GEMM: C[4096 x 2176] = XB[4096x1024] @ WB[2176x1024]^T
// ---------------------------------------------------------------------------
__global__ __launch_bounds__(256) void gemm_mfma(const __bf16* __restrict__ XB,
                                                 const __bf16* __restrict__ WB,
                                                 const float* __restrict__ bq,
                                                 const float* __restrict__ bv,
                                                 const float* __restrict__ bk,
                                                 float* __restrict__ Cq,
                                                 float* __restrict__ Cv,
                                                 float* __restrict__ Kr) {
    __shared__ __bf16 Als[128 * 32];   // 8 KB
    __shared__ __bf16 Bls[128 * 32];   // 8 KB
    const int tid = threadIdx.x;
    const int lane = tid & 63;
    const int w = tid >> 6;
    const int wm = (w & 1) * 64;
    const int wn = (w >> 1) * 64;
    const int rBase = blockIdx.x * 128;
    const int cBase = blockIdx.y * 128;

    const int c0 = tid, c1 = tid + 256;
    const __bf16* gA0 = XB + (size_t)(rBase + (c0 >> 2)) * E_DIM + (c0 & 3) * 8;
    const __bf16* gA1 = XB + (size_t)(rBase + (c1 >> 2)) * E_DIM + (c1 & 3) * 8;
    const __bf16* gB0 = WB + (size_t)(cBase + (c0 >> 2)) * E_DIM + (c0 & 3) * 8;
    const __bf16* gB1 = WB + (size_t)(cBase + (c1 >> 2)) * E_DIM + (c1 & 3) * 8;
    __bf16* lA0 = Als + c0 * 8;
    __bf16* lA1 = Als + c1 * 8;
    __bf16* lB0 = Bls + c0 * 8;
    __bf16* lB1 = Bls + c1 * 8;

    const int fr = lane & 15;
    const int fk = (lane >> 4) * 8;
    const __bf16* aF = Als + (wm + fr) * 32 + fk;
    const __bf16* bF = Bls + (wn + fr) * 32 + fk;

    f32x4 acc[4][4] = {};

    for (int kk = 0; kk < E_DIM; kk += 32) {
        __syncthreads();
        __builtin_amdgcn_global_load_lds(
            (const __attribute__((address_space(1))) void*)(gA0 + kk),
            (__attribute__((address_space(3))) void*)lA0, 16, 0, 0);
        __builtin_amdgcn_global_load_lds(
            (const __attribute__((address_space(1))) void*)(gA1 + kk),
            (__attribute__((address_space(3))) void*)lA1, 16, 0, 0);
        __builtin_amdgcn_global_load_lds(
            (const __attribute__((address_space(1))) void*)(gB0 + kk),
            (__attribute__((address_space(3))) void*)lB0, 16, 0, 0);
        __builtin_amdgcn_global_load_lds(
            (const __attribute__((address_space(1))) void*)(gB1 + kk),
            (__attribute__((address_space(3))) void*)lB1, 16, 0, 0);
        __syncthreads();

        bf16x8 af[4], bfr[4];
#pragma unroll
        for (int mt = 0; mt < 4; ++mt) af[mt] = *(const bf16x8*)(aF + mt * 16 * 32);
#pragma unroll
        for (int nt = 0; nt < 4; ++nt) bfr[nt] = *(const bf16x8*)(bF + nt * 16 * 32);
#pragma unroll
        for (int mt = 0; mt < 4; ++mt)
#pragma unroll
            for (int nt = 0; nt < 4; ++nt)
                acc[mt][nt] = __builtin_amdgcn_mfma_f32_16x16x32_bf16(
                    af[mt], bfr[nt], acc[mt][nt], 0, 0, 0);
    }

    const int row0 = rBase + wm + (lane >> 4) * 4;
    if (cBase < 2048) {
        const float* bias;
        float* Cout;
        int colBase;
        if (cBase < 1024) { bias = bq; Cout = Cq; colBase = cBase; }
        else              { bias = bv; Cout = Cv; colBase = cBase - 1024; }
        const int col0 = colBase + wn + (lane & 15);
#pragma unroll
        for (int mt = 0; mt < 4; ++mt)
#pragma unroll
            for (int nt = 0; nt < 4; ++nt) {
                int cc = col0 + nt * 16;
                float bb = bias[cc];
#pragma unroll
                for (int r = 0; r < 4; ++r)
                    Cout[(size_t)(row0 + mt * 16 + r) * E_DIM + cc] =
                        acc[mt][nt][r] + bb;
            }
    } else {
        const int col0 = wn + (lane & 15);
#pragma unroll
        for (int mt = 0; mt < 4; ++mt)
#pragma unroll
            for (int nt = 0; nt < 4; ++nt) {
                int cc = col0 + nt * 16;
                if (cc < 64) {
                    float bb = bk[cc];
#pragma unroll
                    for (int r = 0; r < 4; ++r)
                        Kr[(size_t)(row0 + mt * 16 + r) * K_DIM + cc] =
                            acc[mt][nt][r] + bb;
                }
            }
    }
}

// ---------------------------------------------------------------------------
// qn -> bf16, layout [b][t][k]. 4 waves x 4 heads each; r = t*B + b.
// ---------------------------------------------------------------------------
__global__ __launch_bounds__(256) void softmax_mean(const float* __restrict__ Q,
                                                    __bf16* __restrict__ QNB) {
    const int r = blockIdx.x;
    const int tid = threadIdx.x;
    const int lane = tid & 63, wv = tid >> 6;
    float acc = 0.f;
#pragma unroll
    for (int h4 = 0; h4 < 4; ++h4) {
        int h = wv * 4 + h4;
        float v = Q[(size_t)r * 1024 + h * 64 + lane];
        float m = v;
#pragma unroll
        for (int off = 32; off; off >>= 1) m = fmaxf(m, __shfl_xor(m, off));
        float e = expf(v - m);
        float ssum = e;
#pragma unroll
        for (int off = 32; off; off >>= 1) ssum += __shfl_xor(ssum, off);
        acc += e / ssum;
    }
    __shared__ float red[4][64];
    red[wv][lane] = acc;
    __syncthreads();
    if (tid < 64) {
        float s = red[0][tid] + red[1][tid] + red[2][tid] + red[3][tid];
        int t = r >> 1, b = r & 1;
        QNB[((size_t)b * T_DIM + t) * K_DIM + tid] = (__bf16)(s * (1.f / 16.f));
    }
}

// ---------------------------------------------------------------------------
// LayerNorm over 64 (for k) -> bf16, layout [b][t][k]; one wave per row.
// ---------------------------------------------------------------------------
__global__ __launch_bounds__(64) void ln64(const float* __restrict__ Kraw,
                                           const float* __restrict__ gamma,
                                           const float* __restrict__ beta,
                                           __bf16* __restrict__ KNB) {
    const int r = blockIdx.x;
    const int lane = threadIdx.x;
    float v = Kraw[(size_t)r * K_DIM + lane];
    float s = v, s2 = v * v;
#pragma unroll
    for (int off = 32; off; off >>= 1) {
        s += __shfl_xor(s, off);
        s2 += __shfl_xor(s2, off);
    }
    float mean = s * (1.f / 64.f);
    float var = s2 * (1.f / 64.f) - mean * mean;
    float inv = rsqrtf(var + 1e-5f);
    int t = r >> 1, b = r & 1;
    KNB[((size_t)b * T_DIM + t) * K_DIM + lane] =
        (__bf16)((v - mean) * inv * gamma[lane] + beta[lane]);
}

// ---------------------------------------------------------------------------
// Row stats for v-LayerNorm: stats[r] = {mean, rsqrt(var+eps)}.
// ---------------------------------------------------------------------------
__global__ __launch_bounds__(256) void vstats(const float* __restrict__ V,
                                              float2* __restrict__ ST) {
    const int r = blockIdx.x;
    const int tid = threadIdx.x;
    const int lane = tid & 63, wv = tid >> 6;
    float4 v = *(const float4*)&V[(size_t)r * E_DIM + tid * 4];
    float s = v.x + v.y + v.z + v.w;
    float s2 = v.x * v.x + v.y * v.y + v.z * v.z + v.w * v.w;
#pragma unroll
    for (int off = 32; off; off >>= 1) {
        s += __shfl_xor(s, off);
        s2 += __shfl_xor(s2, off);
    }
    __shared__ float red[2][4];
    if (lane == 0) { red[0][wv] = s; red[1][wv] = s2; }
    __syncthreads();
    if (tid == 0) {
        s = red[0][0] + red[0][1] + red[0][2] + red[0][3];
        s2 = red[1][0] + red[1][1] + red[1][2] + red[1][3];
        float mean = s * (1.f / 1024.f);
        float var = s2 * (1.f / 1024.f) - mean * mean;
        ST[r] = make_float2(mean, rsqrtf(var + 1e-5f));
    }
}

// ---------------------------------------------------------------------------
// Fused LN + transpose + cvt: v fp32 [t*2+b][e] -> VT bf16 [b][e][t].
// ---------------------------------------------------------------------------
__global__ __launch_bounds__(256) void transpose_lnv(const float* __restrict__ V,
                                                     const float2* __restrict__ ST,
                                                     const float* __restrict__ gamma,
                                                     const float* __restrict__ beta,
                                                     __bf16* __restrict__ VT) {
    __shared__ float tile[64][65];
    const int tb = blockIdx.x, eb = blockIdx.y, b = blockIdx.z;
    const int tid = threadIdx.x;
#pragma unroll
    for (int j = 0; j < 4; ++j) {
        int idx = tid + j * 256;           // 1024 float4
        int tl = idx >> 4, e4 = idx & 15;
        int r = (tb * 64 + tl) * B_DIM + b;
        float2 st = ST[r];
        float4 v = *(const float4*)&V[(size_t)r * E_DIM + eb * 64 + e4 * 4];
        tile[tl][e4 * 4 + 0] = (v.x - st.x) * st.y;
        tile[tl][e4 * 4 + 1] = (v.y - st.x) * st.y;
        tile[tl][e4 * 4 + 2] = (v.z - st.x) * st.y;
        tile[tl][e4 * 4 + 3] = (v.w - st.x) * st.y;
    }
    __syncthreads();
#pragma unroll
    for (int j = 0; j < 4; ++j) {
        int idx = tid + j * 256;           // 1024 groups of 4 t
        int e = idx >> 4, t4 = idx & 15;
        float g = gamma[eb * 64 + e], bb = beta[eb * 64 + e];
        bf16x4 o;
#pragma unroll
        for (int i = 0; i < 4; ++i) o[i] = (__bf16)(tile[t4 * 4 + i][e] * g + bb);
        *(bf16x4*)&VT[((size_t)b * E_DIM + eb * 64 + e) * T_DIM + tb * 64 + t4 * 4] = o;
    }
}

// ---------------------------------------------------------------------------
// scoreK: all causal 128x128 score tiles, masked, bf16, LDS-staged operands.
//   P[b][tile][q][s] = (s_glob<=t_glob) ? qn[t]·kn[s] : 0,  tile=(qt,st)
// Grid (136, B). 4 waves split q (32 each).
// ---------------------------------------------------------------------------
__global__ __launch_bounds__(256) void scoreK(const __bf16* __restrict__ QNB,
                                              const __bf16* __restrict__ KNB,
                                              __bf16* __restrict__ Pg) {
    __shared__ __bf16 qns[128 * 72];   // 18 KB (pad 72: +4 banks/row)
    __shared__ __bf16 kns[128 * 72];   // 18 KB
    const int tileId = blockIdx.x;
    const int b = blockIdx.y;
    int qt = 0, rem = tileId;
    while (rem > qt) { rem -= (qt + 1); ++qt; }
    const int st = rem;
    const int tid = threadIdx.x;
    const int lane = tid & 63;
    const int w = tid >> 6;
    const int qL = lane & 15;
    const int quad = lane >> 4;

    const __bf16* qsrc = QNB + ((size_t)b * T_DIM + qt * 128) * K_DIM;
    const __bf16* ksrc = KNB + ((size_t)b * T_DIM + st * 128) * K_DIM;
#pragma unroll
    for (int j = 0; j < 4; ++j) {
        int idx = tid + j * 256;           // 1024 bf16x8 chunks
        int row = idx >> 3, k8 = idx & 7;
        *(bf16x8*)&qns[row * 72 + k8 * 8] = *(const bf16x8*)&qsrc[row * K_DIM + k8 * 8];
        *(bf16x8*)&kns[row * 72 + k8 * 8] = *(const bf16x8*)&ksrc[row * K_DIM + k8 * 8];
    }
    __syncthreads();

    f32x4 acc[8][2] = {};
#pragma unroll
    for (int kit = 0; kit < 2; ++kit) {
        bf16x8 bfr[2];
#pragma unroll
        for (int nt = 0; nt < 2; ++nt) {
            int q = w * 32 + nt * 16 + qL;
            bfr[nt] = *(const bf16x8*)&qns[q * 72 + kit * 32 + quad * 8];
        }
#pragma unroll
        for (int mt = 0; mt < 8; ++mt) {
            bf16x8 af = *(const bf16x8*)&kns[(mt * 16 + qL) * 72 + kit * 32 + quad * 8];
#pragma unroll
            for (int nt = 0; nt < 2; ++nt)
                acc[mt][nt] = __builtin_amdgcn_mfma_f32_16x16x32_bf16(
                    af, bfr[nt], acc[mt][nt], 0, 0, 0);
        }
    }
    // mask diagonal tile, cvt, packed store
    __bf16* pb = Pg + ((size_t)(b * NTILE + tileId)) * 128 * 128;
#pragma unroll
    for (int mt = 0; mt < 8; ++mt)
#pragma unroll
        for (int nt = 0; nt < 2; ++nt) {
            int q = w * 32 + nt * 16 + qL;
            int s0 = mt * 16 + quad * 4;
            bf16x4 o;
#pragma unroll
            for (int r = 0; r < 4; ++r) {
                float val = acc[mt][nt][r];
                if (qt == st && (s0 + r) > q) val = 0.f;
                o[r] = (__bf16)val;
            }
            *(bf16x4*)&pb[(size_t)q * 128 + s0] = o;
        }
}

// ---------------------------------------------------------------------------
// flashPV: out[t,b,e] = rsqrt(t+1) * sum_{tiles st<=qt} sum_s P[q,s]·v[s,e]
// Grid (8 pairs, 16 es of 64 cols, 2 b) = 256 blocks; pair p covers qt=p then
// qt=15-p -> uniform 17 st-iterations/block. Both operands LDS-staged:
// VT tile [64e][136s] (17.4 KB) + P tile [128q][136s] (34.8 KB).
// 4 waves split q; each: mt(e)=4 x nt(q)=2 x kit=4 = 32 MFMA/iter.
// ---------------------------------------------------------------------------
__global__ __launch_bounds__(256) void flashPV(const __bf16* __restrict__ Pg,
                                               const __bf16* __restrict__ VT,
                                               float* __restrict__ OUT) {
    __shared__ __align__(16) __bf16 vts[64 * 136];    // 17.4 KB (also epilogue scratch)
    __shared__ __align__(16) __bf16 ps[128 * 136];    // 34.8 KB
    const int p = blockIdx.x;
    const int es = blockIdx.y;
    const int b = blockIdx.z;
    const int tid = threadIdx.x;
    const int lane = tid & 63;
    const int w = tid >> 6;
    const int qL = lane & 15;
    const int quad = lane >> 4;

    for (int ph = 0; ph < 2; ++ph) {
        const int qt = ph ? (15 - p) : p;
        const int tileBase = qt * (qt + 1) / 2;
        f32x4 acc[4][2] = {};

        for (int st = 0; st <= qt; ++st) {
            __syncthreads();
            // stage VT tile [64 e][128 s]
#pragma unroll
            for (int j = 0; j < 4; ++j) {
                int idx = tid + j * 256;       // 1024 bf16x8 chunks
                int e = idx >> 4, sc = idx & 15;
                *(bf16x8*)&vts[e * 136 + sc * 8] =
                    *(const bf16x8*)&VT[((size_t)b * E_DIM + es * 64 + e) * T_DIM +
                                        st * 128 + sc * 8];
            }
            // stage P tile [128 q][128 s]
            const __bf16* pb = Pg + ((size_t)(b * NTILE + tileBase + st)) * 128 * 128;
#pragma unroll
            for (int j = 0; j < 8; ++j) {
                int idx = tid + j * 256;       // 2048 bf16x8 chunks
                int q = idx >> 4, sc = idx & 15;
                *(bf16x8*)&ps[q * 136 + sc * 8] = *(const bf16x8*)&pb[q * 128 + sc * 8];
            }
            __syncthreads();
#pragma unroll
            for (int kit = 0; kit < 4; ++kit) {
                bf16x8 bfr[2];
#pragma unroll
                for (int nt = 0; nt < 2; ++nt) {
                    int q = w * 32 + nt * 16 + qL;
                    bfr[nt] = *(const bf16x8*)&ps[q * 136 + kit * 32 + quad * 8];
                }
#pragma unroll
                for (int mt = 0; mt < 4; ++mt) {
                    bf16x8 af = *(const bf16x8*)&vts[(mt * 16 + qL) * 136 + kit * 32 + quad * 8];
#pragma unroll
                    for (int nt = 0; nt < 2; ++nt)
                        acc[mt][nt] = __builtin_amdgcn_mfma_f32_16x16x32_bf16(
                            af, bfr[nt], acc[mt][nt], 0, 0, 0);
                }
            }
        }
        __syncthreads();   // compute done; reuse vts as per-wave transpose scratch

        float* tb = (float*)vts + w * 640;     // [32 q][20 e-slots]
#pragma unroll
        for (int mt = 0; mt < 4; ++mt) {
#pragma unroll
            for (int nt = 0; nt < 2; ++nt)
                *(f32x4*)&tb[(nt * 16 + qL) * 20 + quad * 4] = acc[mt][nt];
#pragma unroll
            for (int j = 0; j < 2; ++j) {
                int fid = lane + j * 64;       // 128 float4 = 32q x 16e
                int q = fid >> 2, e4 = fid & 3;
                float4 val = *(const float4*)&tb[q * 20 + e4 * 4];
                int t = qt * 128 + w * 32 + q;
                float sca = rsqrtf((float)(t + 1));
                float4 r = {val.x * sca, val.y * sca, val.z * sca, val.w * sca};
                *(float4*)&OUT[((size_t)t * B_DIM + b) * E_DIM + es * 64 + mt * 16 + e4 * 4] = r;
            }
        }
    }
}

// ---------------------------------------------------------------------------
extern "C" void kernel_launch(void* const* d_in, const int* in_sizes, int n_in,
                              void* d_out, int out_size, void* d_ws,
                              size_t ws_size, hipStream_t stream) {
    const float* x = (const float*)d_in[0];
    const float* Wq = (const float*)d_in[2];
    const float* bq = (const float*)d_in[3];
    const float* Wk = (const float*)d_in[4];
    const float* bk = (const float*)d_in[5];
    const float* Wv = (const float*)d_in[6];
    const float* bv = (const float*)d_in[7];
    const float* kg = (const float*)d_in[8];
    const float* kb = (const float*)d_in[9];
    const float* vg = (const float*)d_in[10];
    const float* vb = (const float*)d_in[11];
    float* out = (float*)d_out;

    float* ws = (float*)d_ws;
    float* qraw = ws;                              // 4M floats (16 MB)
    float* v = ws + (size_t)4 * 1024 * 1024;       // 4M floats (16 MB)
    float* kraw = ws + (size_t)8 * 1024 * 1024;    // 256K floats (1 MB)
    __bf16* xb = (__bf16*)(kraw + 256 * 1024);     // 4M bf16 (8 MB)
    __bf16* wb = xb + (size_t)4 * 1024 * 1024;     // WROWS*1024 bf16 (4.46 MB)
    __bf16* qnb = wb + (size_t)WROWS * 1024;       // [b][t][64] (0.5 MB)
    __bf16* knb = qnb + 256 * 1024;                // [b][t][64] (0.5 MB)
    float2* stats = (float2*)(knb + 256 * 1024);   // [4096] row stats (32 KB)
    // aliases (dead regions):
    __bf16* Pg = (__bf16*)qraw;                    // 136*2*16384 bf16 (8.9 MB), after softmax
    __bf16* vbT = xb;                              // [b][e][t] bf16 (8 MB), after gemm

    // bf16 conversions
    cvt_x<<<dim3(2048), 256, 0, stream>>>(x, xb);
    cvt_w<<<dim3(WROWS * 1024 / 8 / 256), 256, 0, stream>>>(Wq, Wv, Wk, wb);
    // fused q|v|k projection via MFMA
    gemm_mfma<<<dim3(32, 17), 256, 0, stream>>>(xb, wb, bq, bv, bk, qraw, v, kraw);
    // epilogues -> bf16 operands
    softmax_mean<<<dim3(R_DIM), 256, 0, stream>>>(qraw, qnb);
    ln64<<<dim3(R_DIM), 64, 0, stream>>>(kraw, kg, kb, knb);
    vstats<<<dim3(R_DIM), 256, 0, stream>>>(v, stats);
    transpose_lnv<<<dim3(T_DIM / 64, E_DIM / 64, B_DIM), 256, 0, stream>>>(
        v, stats, vg, vb, vbT);
    // causal attention tail via MFMA
    scoreK<<<dim3(NTILE, B_DIM), 256, 0, stream>>>(qnb, knb, Pg);
    flashPV<<<dim3(8, 16, B_DIM), 256, 0, stream>>>(Pg, vbT, out);
}

// Round 8
// 186.639 us; speedup vs baseline: 1.3451x; 1.0282x over previous
//
#include <hip/hip_runtime.h>
#include <math.h>

#define T_DIM 2048
#define B_DIM 2
#define E_DIM 1024
#define K_DIM 64
#define H_DIM 16
#define R_DIM (T_DIM * B_DIM)   // 4096 rows, row r = t*B + b
#define WROWS 2176              // Wq(1024) + Wv(1024) + Wk(64) + pad(64)
#define NTILE 136               // 16*17/2 causal (qt,st) tile pairs

typedef __bf16 bf16x8 __attribute__((ext_vector_type(8)));
typedef __bf16 bf16x4 __attribute__((ext_vector_type(4)));
typedef float f32x4 __attribute__((ext_vector_type(4)));

// ---------------------------------------------------------------------------
// Fused fp32->bf16 conversion: blocks [0,2048) convert x (4M elems);
// blocks [2048,3136) convert W-concat [Wq;Wv;Wk;pad] (2176*1024 elems).
// ---------------------------------------------------------------------------
__global__ __launch_bounds__(256) void cvt_all(const float* __restrict__ X,
                                               const float* __restrict__ Wq,
                                               const float* __restrict__ Wv,
                                               const float* __restrict__ Wk,
                                               __bf16* __restrict__ XB,
                                               __bf16* __restrict__ WB) {
    const size_t nq = (size_t)1024 * 1024;
    const size_t nk = (size_t)64 * 1024;
    bf16x8 o;
    if (blockIdx.x < 2048) {
        size_t g = ((size_t)blockIdx.x * 256 + threadIdx.x) * 8;
        float4 a = *(const float4*)&X[g];
        float4 b = *(const float4*)&X[g + 4];
        o[0] = (__bf16)a.x; o[1] = (__bf16)a.y; o[2] = (__bf16)a.z; o[3] = (__bf16)a.w;
        o[4] = (__bf16)b.x; o[5] = (__bf16)b.y; o[6] = (__bf16)b.z; o[7] = (__bf16)b.w;
        *(bf16x8*)&XB[g] = o;
    } else {
        size_t g = ((size_t)(blockIdx.x - 2048) * 256 + threadIdx.x) * 8;
        if (g < 2 * nq + nk) {
            const float* src;
            size_t off;
            if (g < nq)          { src = Wq; off = g; }
            else if (g < 2 * nq) { src = Wv; off = g - nq; }
            else                 { src = Wk; off = g - 2 * nq; }
            float4 a = *(const float4*)&src[off];
            float4 b = *(const float4*)&src[off + 4];
            o[0] = (__bf16)a.x; o[1] = (__bf16)a.y; o[2] = (__bf16)a.z; o[3] = (__bf16)a.w;
            o[4] = (__bf16)b.x; o[5] = (__bf16)b.y; o[6] = (__bf16)b.z; o[7] = (__bf16)b.w;
        } else {
#pragma unroll
            for (int i = 0; i < 8; ++i) o[i] = (__bf16)0.f;
        }
        *(bf16x8*)&WB[g] = o;
    }
}

// ---------------------------------------------------------------------------
// bf16 MFMA GEMM: C[4096 x 2176] = XB[4096x1024] @ WB[2176x1024]^T
// Cols <1024 -> Qb bf16 (+bq); <2048 -> Vb bf16 (+bv); else 64 -> Kr fp32 (+bk).
// ---------------------------------------------------------------------------
__global__ __launch_bounds__(256) void gemm_mfma(const __bf16* __restrict__ XB,
                                                 const __bf16* __restrict__ WB,
                                                 const float* __restrict__ bq,
                                                 const float* __restrict__ bv,
                                                 const float* __restrict__ bk,
                                                 __bf16* __restrict__ Qb,
                                                 __bf16* __restrict__ Vb,
                                                 float* __restrict__ Kr) {
    __shared__ __bf16 Als[128 * 32];   // 8 KB
    __shared__ __bf16 Bls[128 * 32];   // 8 KB
    const int tid = threadIdx.x;
    const int lane = tid & 63;
    const int w = tid >> 6;
    const int wm = (w & 1) * 64;
    const int wn = (w >> 1) * 64;
    const int rBase = blockIdx.x * 128;
    const int cBase = blockIdx.y * 128;

    const int c0 = tid, c1 = tid + 256;
    const __bf16* gA0 = XB + (size_t)(rBase + (c0 >> 2)) * E_DIM + (c0 & 3) * 8;
    const __bf16* gA1 = XB + (size_t)(rBase + (c1 >> 2)) * E_DIM + (c1 & 3) * 8;
    const __bf16* gB0 = WB + (size_t)(cBase + (c0 >> 2)) * E_DIM + (c0 & 3) * 8;
    const __bf16* gB1 = WB + (size_t)(cBase + (c1 >> 2)) * E_DIM + (c1 & 3) * 8;
    __bf16* lA0 = Als + c0 * 8;
    __bf16* lA1 = Als + c1 * 8;
    __bf16* lB0 = Bls + c0 * 8;
    __bf16* lB1 = Bls + c1 * 8;

    const int fr = lane & 15;
    const int fk = (lane >> 4) * 8;
    const __bf16* aF = Als + (wm + fr) * 32 + fk;
    const __bf16* bF = Bls + (wn + fr) * 32 + fk;

    f32x4 acc[4][4] = {};

    for (int kk = 0; kk < E_DIM; kk += 32) {
        __syncthreads();
        __builtin_amdgcn_global_load_lds(
            (const __attribute__((address_space(1))) void*)(gA0 + kk),
            (__attribute__((address_space(3))) void*)lA0, 16, 0, 0);
        __builtin_amdgcn_global_load_lds(
            (const __attribute__((address_space(1))) void*)(gA1 + kk),
            (__attribute__((address_space(3))) void*)lA1, 16, 0, 0);
        __builtin_amdgcn_global_load_lds(
            (const __attribute__((address_space(1))) void*)(gB0 + kk),
            (__attribute__((address_space(3))) void*)lB0, 16, 0, 0);
        __builtin_amdgcn_global_load_lds(
            (const __attribute__((address_space(1))) void*)(gB1 + kk),
            (__attribute__((address_space(3))) void*)lB1, 16, 0, 0);
        __syncthreads();

        bf16x8 af[4], bfr[4];
#pragma unroll
        for (int mt = 0; mt < 4; ++mt) af[mt] = *(const bf16x8*)(aF + mt * 16 * 32);
#pragma unroll
        for (int nt = 0; nt < 4; ++nt) bfr[nt] = *(const bf16x8*)(bF + nt * 16 * 32);
#pragma unroll
        for (int mt = 0; mt < 4; ++mt)
#pragma unroll
            for (int nt = 0; nt < 4; ++nt)
                acc[mt][nt] = __builtin_amdgcn_mfma_f32_16x16x32_bf16(
                    af[mt], bfr[nt], acc[mt][nt], 0, 0, 0);
    }

    const int row0 = rBase + wm + (lane >> 4) * 4;
    if (cBase < 2048) {
        const float* bias;
        __bf16* Cout;
        int colBase;
        if (cBase < 1024) { bias = bq; Cout = Qb; colBase = cBase; }
        else              { bias = bv; Cout = Vb; colBase = cBase - 1024; }
        const int col0 = colBase + wn + (lane & 15);
#pragma unroll
        for (int mt = 0; mt < 4; ++mt)
#pragma unroll
            for (int nt = 0; nt < 4; ++nt) {
                int cc = col0 + nt * 16;
                float bb = bias[cc];
#pragma unroll
                for (int r = 0; r < 4; ++r)
                    Cout[(size_t)(row0 + mt * 16 + r) * E_DIM + cc] =
                        (__bf16)(acc[mt][nt][r] + bb);
            }
    } else {
        const int col0 = wn + (lane & 15);
#pragma unroll
        for (int mt = 0; mt < 4; ++mt)
#pragma unroll
            for (int nt = 0; nt < 4; ++nt) {
                int cc = col0 + nt * 16;
                if (cc < 64) {
                    float bb = bk[cc];
#pragma unroll
                    for (int r = 0; r < 4; ++r)
                        Kr[(size_t)(row0 + mt * 16 + r) * K_DIM + cc] =
                            acc[mt][nt][r] + bb;
                }
            }
    }
}

// ---------------------------------------------------------------------------
// Fused row epilogues, one block per row r = t*B + b:
//  - qn[b][t][k] = mean_h softmax_k(qb[r, h*64+k])        (waves 0-3 + finalize)
//  - knb[b][t][k] = LN64(kraw[r])                          (wave 1 after sync)
//  - stats[r] = {mean, rsqrt(var+eps)} of vb[r]            (thread 128 finalize)
// ---------------------------------------------------------------------------
__global__ __launch_bounds__(256) void rowops(const __bf16* __restrict__ Qb,
                                              const float* __restrict__ Kraw,
                                              const __bf16* __restrict__ Vb,
                                              const float* __restrict__ kg,
                                              const float* __restrict__ kb,
                                              __bf16* __restrict__ QNB,
                                              __bf16* __restrict__ KNB,
                                              float2* __restrict__ ST) {
    const int r = blockIdx.x;
    const int tid = threadIdx.x;
    const int lane = tid & 63, wv = tid >> 6;
    const int t = r >> 1, b = r & 1;
    __shared__ float redq[4][64];
    __shared__ float redv[2][4];

    // softmax partials: wave wv handles heads wv*4 .. wv*4+3
    float acc = 0.f;
#pragma unroll
    for (int h4 = 0; h4 < 4; ++h4) {
        int h = wv * 4 + h4;
        float v = (float)Qb[(size_t)r * 1024 + h * 64 + lane];
        float m = v;
#pragma unroll
        for (int off = 32; off; off >>= 1) m = fmaxf(m, __shfl_xor(m, off));
        float e = expf(v - m);
        float ssum = e;
#pragma unroll
        for (int off = 32; off; off >>= 1) ssum += __shfl_xor(ssum, off);
        acc += e / ssum;
    }
    redq[wv][lane] = acc;

    // v-stats partials: 4 bf16 per thread
    {
        bf16x4 v4 = *(const bf16x4*)&Vb[(size_t)r * 1024 + tid * 4];
        float a = (float)v4[0], c = (float)v4[1], d = (float)v4[2], e = (float)v4[3];
        float s = a + c + d + e;
        float s2 = a * a + c * c + d * d + e * e;
#pragma unroll
        for (int off = 32; off; off >>= 1) {
            s += __shfl_xor(s, off);
            s2 += __shfl_xor(s2, off);
        }
        if (lane == 0) { redv[0][wv] = s; redv[1][wv] = s2; }
    }
    __syncthreads();

    if (tid < 64) {
        float s = redq[0][tid] + redq[1][tid] + redq[2][tid] + redq[3][tid];
        QNB[((size_t)b * T_DIM + t) * K_DIM + tid] = (__bf16)(s * (1.f / 16.f));
    } else if (tid < 128) {
        // LN64 on kraw (wave 1)
        float v = Kraw[(size_t)r * K_DIM + lane];
        float s = v, s2 = v * v;
#pragma unroll
        for (int off = 32; off; off >>= 1) {
            s += __shfl_xor(s, off);
            s2 += __shfl_xor(s2, off);
        }
        float mean = s * (1.f / 64.f);
        float var = s2 * (1.f / 64.f) - mean * mean;
        float inv = rsqrtf(var + 1e-5f);
        KNB[((size_t)b * T_DIM + t) * K_DIM + lane] =
            (__bf16)((v - mean) * inv * kg[lane] + kb[lane]);
    } else if (tid == 128) {
        float s = redv[0][0] + redv[0][1] + redv[0][2] + redv[0][3];
        float s2 = redv[1][0] + redv[1][1] + redv[1][2] + redv[1][3];
        float mean = s * (1.f / 1024.f);
        float var = s2 * (1.f / 1024.f) - mean * mean;
        ST[r] = make_float2(mean, rsqrtf(var + 1e-5f));
    }
}

// ---------------------------------------------------------------------------
// Fused LN + transpose: vb bf16 [t*2+b][e] -> VT bf16 [b][e][t].
// ---------------------------------------------------------------------------
__global__ __launch_bounds__(256) void transpose_lnv(const __bf16* __restrict__ VB,
                                                     const float2* __restrict__ ST,
                                                     const float* __restrict__ gamma,
                                                     const float* __restrict__ beta,
                                                     __bf16* __restrict__ VT) {
    __shared__ float tile[64][65];
    const int tb = blockIdx.x, eb = blockIdx.y, b = blockIdx.z;
    const int tid = threadIdx.x;
#pragma unroll
    for (int j = 0; j < 2; ++j) {
        int idx = tid + j * 256;           // 512 chunks of 8 bf16
        int tl = idx >> 3, e8 = idx & 7;
        int r = (tb * 64 + tl) * B_DIM + b;
        float2 st = ST[r];
        bf16x8 v = *(const bf16x8*)&VB[(size_t)r * E_DIM + eb * 64 + e8 * 8];
#pragma unroll
        for (int i = 0; i < 8; ++i)
            tile[tl][e8 * 8 + i] = ((float)v[i] - st.x) * st.y;
    }
    __syncthreads();
#pragma unroll
    for (int j = 0; j < 4; ++j) {
        int idx = tid + j * 256;           // 1024 groups of 4 t
        int e = idx >> 4, t4 = idx & 15;
        float g = gamma[eb * 64 + e], bb = beta[eb * 64 + e];
        bf16x4 o;
#pragma unroll
        for (int i = 0; i < 4; ++i) o[i] = (__bf16)(tile[t4 * 4 + i][e] * g + bb);
        *(bf16x4*)&VT[((size_t)b * E_DIM + eb * 64 + e) * T_DIM + tb * 64 + t4 * 4] = o;
    }
}

// ---------------------------------------------------------------------------
// scoreK: all causal 128x128 score tiles, masked, bf16, LDS-staged operands.
// ---------------------------------------------------------------------------
__global__ __launch_bounds__(256) void scoreK(const __bf16* __restrict__ QNB,
                                              const __bf16* __restrict__ KNB,
                                              __bf16* __restrict__ Pg) {
    __shared__ __bf16 qns[128 * 72];   // 18 KB
    __shared__ __bf16 kns[128 * 72];   // 18 KB
    const int tileId = blockIdx.x;
    const int b = blockIdx.y;
    int qt = 0, rem = tileId;
    while (rem > qt) { rem -= (qt + 1); ++qt; }
    const int st = rem;
    const int tid = threadIdx.x;
    const int lane = tid & 63;
    const int w = tid >> 6;
    const int qL = lane & 15;
    const int quad = lane >> 4;

    const __bf16* qsrc = QNB + ((size_t)b * T_DIM + qt * 128) * K_DIM;
    const __bf16* ksrc = KNB + ((size_t)b * T_DIM + st * 128) * K_DIM;
#pragma unroll
    for (int j = 0; j < 4; ++j) {
        int idx = tid + j * 256;
        int row = idx >> 3, k8 = idx & 7;
        *(bf16x8*)&qns[row * 72 + k8 * 8] = *(const bf16x8*)&qsrc[row * K_DIM + k8 * 8];
        *(bf16x8*)&kns[row * 72 + k8 * 8] = *(const bf16x8*)&ksrc[row * K_DIM + k8 * 8];
    }
    __syncthreads();

    f32x4 acc[8][2] = {};
#pragma unroll
    for (int kit = 0; kit < 2; ++kit) {
        bf16x8 bfr[2];
#pragma unroll
        for (int nt = 0; nt < 2; ++nt) {
            int q = w * 32 + nt * 16 + qL;
            bfr[nt] = *(const bf16x8*)&qns[q * 72 + kit * 32 + quad * 8];
        }
#pragma unroll
        for (int mt = 0; mt < 8; ++mt) {
            bf16x8 af = *(const bf16x8*)&kns[(mt * 16 + qL) * 72 + kit * 32 + quad * 8];
#pragma unroll
            for (int nt = 0; nt < 2; ++nt)
                acc[mt][nt] = __builtin_amdgcn_mfma_f32_16x16x32_bf16(
                    af, bfr[nt], acc[mt][nt], 0, 0, 0);
        }
    }
    __bf16* pb = Pg + ((size_t)(b * NTILE + tileId)) * 128 * 128;
#pragma unroll
    for (int mt = 0; mt < 8; ++mt)
#pragma unroll
        for (int nt = 0; nt < 2; ++nt) {
            int q = w * 32 + nt * 16 + qL;
            int s0 = mt * 16 + quad * 4;
            bf16x4 o;
#pragma unroll
            for (int r = 0; r < 4; ++r) {
                float val = acc[mt][nt][r];
                if (qt == st && (s0 + r) > q) val = 0.f;
                o[r] = (__bf16)val;
            }
            *(bf16x4*)&pb[(size_t)q * 128 + s0] = o;
        }
}

// ---------------------------------------------------------------------------
// flashPV: out[t,b,e] = rsqrt(t+1) * sum_{tiles st<=qt} sum_s P[q,s]·v[s,e]
// Grid (8 pairs, 16 es, 2 b); pair p covers qt=p then 15-p (uniform 17 iters).
// ---------------------------------------------------------------------------
__global__ __launch_bounds__(256) void flashPV(const __bf16* __restrict__ Pg,
                                               const __bf16* __restrict__ VT,
                                               float* __restrict__ OUT) {
    __shared__ __align__(16) __bf16 vts[64 * 136];    // 17.4 KB (+ epilogue scratch)
    __shared__ __align__(16) __bf16 ps[128 * 136];    // 34.8 KB
    const int p = blockIdx.x;
    const int es = blockIdx.y;
    const int b = blockIdx.z;
    const int tid = threadIdx.x;
    const int lane = tid & 63;
    const int w = tid >> 6;
    const int qL = lane & 15;
    const int quad = lane >> 4;

    for (int ph = 0; ph < 2; ++ph) {
        const int qt = ph ? (15 - p) : p;
        const int tileBase = qt * (qt + 1) / 2;
        f32x4 acc[4][2] = {};

        for (int st = 0; st <= qt; ++st) {
            __syncthreads();
#pragma unroll
            for (int j = 0; j < 4; ++j) {
                int idx = tid + j * 256;
                int e = idx >> 4, sc = idx & 15;
                *(bf16x8*)&vts[e * 136 + sc * 8] =
                    *(const bf16x8*)&VT[((size_t)b * E_DIM + es * 64 + e) * T_DIM +
                                        st * 128 + sc * 8];
            }
            const __bf16* pb = Pg + ((size_t)(b * NTILE + tileBase + st)) * 128 * 128;
#pragma unroll
            for (int j = 0; j < 8; ++j) {
                int idx = tid + j * 256;
                int q = idx >> 4, sc = idx & 15;
                *(bf16x8*)&ps[q * 136 + sc * 8] = *(const bf16x8*)&pb[q * 128 + sc * 8];
            }
            __syncthreads();
#pragma unroll
            for (int kit = 0; kit < 4; ++kit) {
                bf16x8 bfr[2];
#pragma unroll
                for (int nt = 0; nt < 2; ++nt) {
                    int q = w * 32 + nt * 16 + qL;
                    bfr[nt] = *(const bf16x8*)&ps[q * 136 + kit * 32 + quad * 8];
                }
#pragma unroll
                for (int mt = 0; mt < 4; ++mt) {
                    bf16x8 af = *(const bf16x8*)&vts[(mt * 16 + qL) * 136 + kit * 32 + quad * 8];
#pragma unroll
                    for (int nt = 0; nt < 2; ++nt)
                        acc[mt][nt] = __builtin_amdgcn_mfma_f32_16x16x32_bf16(
                            af, bfr[nt], acc[mt][nt], 0, 0, 0);
                }
            }
        }
        __syncthreads();   // compute done; reuse vts as per-wave transpose scratch

        float* tb = (float*)vts + w * 640;     // [32 q][20 e-slots]
#pragma unroll
        for (int mt = 0; mt < 4; ++mt) {
#pragma unroll
            for (int nt = 0; nt < 2; ++nt)
                *(f32x4*)&tb[(nt * 16 + qL) * 20 + quad * 4] = acc[mt][nt];
#pragma unroll
            for (int j = 0; j < 2; ++j) {
                int fid = lane + j * 64;       // 128 float4 = 32q x 16e
                int q = fid >> 2, e4 = fid & 3;
                float4 val = *(const float4*)&tb[q * 20 + e4 * 4];
                int t = qt * 128 + w * 32 + q;
                float sca = rsqrtf((float)(t + 1));
                float4 r = {val.x * sca, val.y * sca, val.z * sca, val.w * sca};
                *(float4*)&OUT[((size_t)t * B_DIM + b) * E_DIM + es * 64 + mt * 16 + e4 * 4] = r;
            }
        }
    }
}

// ---------------------------------------------------------------------------
extern "C" void kernel_launch(void* const* d_in, const int* in_sizes, int n_in,
                              void* d_out, int out_size, void* d_ws,
                              size_t ws_size, hipStream_t stream) {
    const float* x = (const float*)d_in[0];
    const float* Wq = (const float*)d_in[2];
    const float* bq = (const float*)d_in[3];
    const float* Wk = (const float*)d_in[4];
    const float* bk = (const float*)d_in[5];
    const float* Wv = (const float*)d_in[6];
    const float* bv = (const float*)d_in[7];
    const float* kg = (const float*)d_in[8];
    const float* kb = (const float*)d_in[9];
    const float* vg = (const float*)d_in[10];
    const float* vb = (const float*)d_in[11];
    float* out = (float*)d_out;

    char* base = (char*)d_ws;
    const size_t MB = 1024 * 1024;
    __bf16* qb    = (__bf16*)(base + 0);         // [r][e] bf16, 8 MB
    __bf16* vbuf  = (__bf16*)(base + 8 * MB);    // [r][e] bf16, 8 MB
    float*  kraw  = (float*)(base + 16 * MB);    // [r][64] fp32, 1 MB
    __bf16* xb    = (__bf16*)(base + 17 * MB);   // 8 MB
    __bf16* wb    = (__bf16*)(base + 25 * MB);   // 4.46 MB
    __bf16* qnb   = (__bf16*)(base + 30 * MB);   // [b][t][64], 0.5 MB
    __bf16* knb   = (__bf16*)(base + 31 * MB);   // [b][t][64], 0.5 MB
    float2* stats = (float2*)(base + 32 * MB);   // 32 KB
    // aliases of dead regions:
    __bf16* Pg  = (__bf16*)(base + 0);           // 8.9 MB (qb+vbuf dead after transpose)
    __bf16* vbT = xb;                            // [b][e][t], 8 MB (xb dead after gemm)

    cvt_all<<<dim3(2048 + WROWS * 1024 / 2048), 256, 0, stream>>>(x, Wq, Wv, Wk, xb, wb);
    gemm_mfma<<<dim3(32, 17), 256, 0, stream>>>(xb, wb, bq, bv, bk, qb, vbuf, kraw);
    rowops<<<dim3(R_DIM), 256, 0, stream>>>(qb, kraw, vbuf, kg, kb, qnb, knb, stats);
    transpose_lnv<<<dim3(T_DIM / 64, E_DIM / 64, B_DIM), 256, 0, stream>>>(
        vbuf, stats, vg, vb, vbT);
    scoreK<<<dim3(NTILE, B_DIM), 256, 0, stream>>>(qnb, knb, Pg);
    flashPV<<<dim3(8, 16, B_DIM), 256, 0, stream>>>(Pg, vbT, out);
}